// Round 14
// baseline (114.911 us; speedup 1.0000x reference)
//
#include <hip/hip_runtime.h>
#include <stdint.h>

#define B_SZ 2048
#define F_SZ 24
#define E_SZ 128
#define P_SZ 276            // F*(F-1)/2
#define NWG  (P_SZ * 4)     // 1104: (pair, 512-row batch quarter)

#define XT_ELEMS (B_SZ * F_SZ * E_SZ)   // 6,291,456 (12.6 MB bf16)
#define WS_NEED  ((size_t)XT_ELEMS * 2)

#define XPREP_BLKS (F_SZ * 64)          // 1536  (one per (f, 32-row group))

typedef __bf16 bf16x8 __attribute__((ext_vector_type(8)));
typedef __bf16 bf16x4 __attribute__((ext_vector_type(4)));
typedef float  f32x16 __attribute__((ext_vector_type(16)));

// ---- prepack: x only --------------------------------------------------------
// xft[f][grp<64][slot<512][8]: slot s holds
//   x[grp*32 + (s&31)][f][(s>>6)*16 + ((s>>5)&1)*8 + i]   (bf16)
// Serves MFMA B-fragments (slot = kk*64 + lane) and epilogue Xq reads
// (slot = (2mt+(q>>1))*64 + (q&1)*32 + l31, elem hi*4+i), both coalesced.
__global__ __launch_bounds__(256) void prepack_x(
    const float* __restrict__ x, __bf16* __restrict__ xft)
{
    const int bid = blockIdx.x;
    const int tid = threadIdx.x;
    const int f = bid >> 6, grp = bid & 63;
    __shared__ float sT[32][129];           // +1 pad: conflict-free col reads
    {
        const int row = tid >> 3, c0 = (tid & 7) * 16;
        const float* src = x + ((size_t)(grp * 32 + row) * F_SZ + f) * E_SZ + c0;
        float4 v0 = ((const float4*)src)[0];
        float4 v1 = ((const float4*)src)[1];
        float4 v2 = ((const float4*)src)[2];
        float4 v3 = ((const float4*)src)[3];
        *(float4*)&sT[row][c0]      = v0;
        *(float4*)&sT[row][c0 + 4]  = v1;
        *(float4*)&sT[row][c0 + 8]  = v2;
        *(float4*)&sT[row][c0 + 12] = v3;
    }
    __syncthreads();
    __bf16* dst = xft + (size_t)(f * 64 + grp) * 4096;
#pragma unroll
    for (int u = 0; u < 2; ++u) {
        const int s = tid * 2 + u;          // slot 0..511
        const int row = s & 31;
        const int e0  = (s >> 6) * 16 + ((s >> 5) & 1) * 8;
        bf16x8 h;
#pragma unroll
        for (int i = 0; i < 8; ++i)
            h[i] = (__bf16)sT[row][e0 + i];
        *(bf16x8*)(dst + s * 8) = h;
    }
}

// ---- main: one block = (pair p, 512-row batch quarter).
//      Phase 1: K_p f32 -> swizzled bf16 LDS (coalesced, 1 barrier), then
//      each wave pulls ALL 32 A-fragments into 64 VGPRs (whole K in regs).
//      Phase 2: two 256-row tiles, ZERO LDS traffic: 24 coalesced x loads +
//      32 MFMA + lane-local dot per tile. Tile-0 x loads issued before
//      phase 1 so they complete under the K conversion.
__global__ __launch_bounds__(512, 4) void opn_main(
    const __bf16* __restrict__ xft, const float* __restrict__ kern,
    float* __restrict__ out)
{
    __shared__ short sK[E_SZ * E_SZ];   // 32 KB swizzled K_p (phase 1 only)

    const int tid = threadIdx.x, w = tid >> 6, lane = tid & 63;
    const int l31 = lane & 31, hi = lane >> 5;
    const int orig = blockIdx.x;
    const int bb2 = orig & 3;           // batch quarter -> XCD-resident x slice
    const int p   = orig >> 2;          // 0..275 (4 same-pair blocks adjacent)

    int fp = 0, rem = p;
    while (rem >= F_SZ - 1 - fp) { rem -= F_SZ - 1 - fp; ++fp; }
    const int fq = fp + 1 + rem;

    // ---- tile-0 x loads issued EARLY (complete under phase 1) ----
    bf16x8 xpf[8];
    bf16x4 xqr[4][4];
    {
        const int grp = bb2 * 16 + w;   // tile 0: 32-row batch group
        const __bf16* xpb = xft + (size_t)(fp * 64 + grp) * 4096 + lane * 8;
#pragma unroll
        for (int kk = 0; kk < 8; ++kk)
            xpf[kk] = *(const bf16x8*)(xpb + kk * 512);
        const __bf16* xqb = xft + (size_t)(fq * 64 + grp) * 4096 + l31 * 8 + hi * 4;
#pragma unroll
        for (int mt = 0; mt < 4; ++mt)
#pragma unroll
            for (int q = 0; q < 4; ++q)
                xqr[mt][q] = *(const bf16x4*)(xqb + (mt * 2 + (q >> 1)) * 512 + (q & 1) * 256);
    }

    // ---- phase 1: K_p f32 -> bf16, XOR-swizzled into LDS (coalesced) ----
    {
        const int d = tid >> 2, c = tid & 3;    // row d, 32-f32 chunk c
        const float* kr = kern + ((size_t)d * P_SZ + p) * E_SZ + c * 32;
        float4 v[8];
#pragma unroll
        for (int j = 0; j < 8; ++j) v[j] = ((const float4*)kr)[j];
        const int dsw = d & 15;
#pragma unroll
        for (int j = 0; j < 4; ++j) {
            bf16x8 hh;
            hh[0] = (__bf16)v[2*j].x;   hh[1] = (__bf16)v[2*j].y;
            hh[2] = (__bf16)v[2*j].z;   hh[3] = (__bf16)v[2*j].w;
            hh[4] = (__bf16)v[2*j+1].x; hh[5] = (__bf16)v[2*j+1].y;
            hh[6] = (__bf16)v[2*j+1].z; hh[7] = (__bf16)v[2*j+1].w;
            const int s = c * 4 + j;            // source 16B-slot
            *(bf16x8*)&sK[d * E_SZ + ((s ^ dsw) << 3)] = hh;
        }
    }
    __syncthreads();

    // ---- pull the whole K into registers: 32 A-fragments = 64 VGPRs ----
    bf16x8 kf[4][8];
#pragma unroll
    for (int mt = 0; mt < 4; ++mt) {
        const int arow = mt * 32 + l31;
        const short* kRow = &sK[arow * E_SZ];
        const int asw = (arow & 15) << 3;
#pragma unroll
        for (int kk = 0; kk < 8; ++kk)
            kf[mt][kk] = *(const bf16x8*)&kRow[((kk * 2 + hi) << 3) ^ asw];
    }

    // ---- phase 2: two 256-row tiles, no LDS, no barriers ----
#pragma unroll
    for (int t = 0; t < 2; ++t) {
        const int grp = bb2 * 16 + t * 8 + w;
        if (t > 0) {                    // tile-1 x loads (tile-0 preloaded)
            const __bf16* xpb = xft + (size_t)(fp * 64 + grp) * 4096 + lane * 8;
#pragma unroll
            for (int kk = 0; kk < 8; ++kk)
                xpf[kk] = *(const bf16x8*)(xpb + kk * 512);
            const __bf16* xqb = xft + (size_t)(fq * 64 + grp) * 4096 + l31 * 8 + hi * 4;
#pragma unroll
            for (int mt = 0; mt < 4; ++mt)
#pragma unroll
                for (int q = 0; q < 4; ++q)
                    xqr[mt][q] = *(const bf16x4*)(xqb + (mt * 2 + (q >> 1)) * 512 + (q & 1) * 256);
        }

        // D layout: col = lane&31 (= b), row(d) = (reg&3)+8*(reg>>2)+4*hi+32mt
        float s0 = 0.f, s1 = 0.f;
#pragma unroll
        for (int mt = 0; mt < 4; ++mt) {
            f32x16 acc;
#pragma unroll
            for (int q = 0; q < 16; ++q) acc[q] = 0.f;
#pragma unroll
            for (int kk = 0; kk < 8; ++kk)
                acc = __builtin_amdgcn_mfma_f32_32x32x16_bf16(kf[mt][kk], xpf[kk], acc, 0, 0, 0);
#pragma unroll
            for (int q = 0; q < 4; ++q) {
                const bf16x4 xq = xqr[mt][q];
                s0 += acc[q * 4 + 0] * (float)xq[0] + acc[q * 4 + 1] * (float)xq[1];
                s1 += acc[q * 4 + 2] * (float)xq[2] + acc[q * 4 + 3] * (float)xq[3];
            }
        }
        float s = s0 + s1;
        s += __shfl_xor(s, 32);         // combine the two hi row-groups
        if (hi == 0)
            out[(size_t)(grp * 32 + l31) * P_SZ + p] = s;
    }
}

// ---------------- fallback (round-2 kernel, used if ws too small) -----------
__global__ __launch_bounds__(512, 4) void opn_fallback(
    const float* __restrict__ x, const float* __restrict__ kern,
    float* __restrict__ out)
{
    __shared__ short sA[128 * E_SZ];
    __shared__ short sB[E_SZ * E_SZ];
    __shared__ float red[2][128];

    const int tid = threadIdx.x;
    const int orig = blockIdx.x;
    const int nwg2 = P_SZ * 16;
    const int wgid = (orig & 7) * (nwg2 / 8) + (orig >> 3);
    const int p  = wgid >> 4;
    const int bb = wgid & 15;
    const int b0 = bb * 128;

    int fp = 0, rem = p;
    while (rem >= F_SZ - 1 - fp) { rem -= F_SZ - 1 - fp; ++fp; }
    const int fq = fp + 1 + rem;

#pragma unroll
    for (int k = 0; k < 4; ++k) {
        int i = tid + k * 512;
        int r = i >> 4, s8 = i & 15;
        const float* src = x + ((size_t)(b0 + r) * F_SZ + fp) * E_SZ + s8 * 8;
        float4 v0 = *(const float4*)src;
        float4 v1 = *(const float4*)(src + 4);
        bf16x8 hh;
        hh[0] = (__bf16)v0.x; hh[1] = (__bf16)v0.y; hh[2] = (__bf16)v0.z; hh[3] = (__bf16)v0.w;
        hh[4] = (__bf16)v1.x; hh[5] = (__bf16)v1.y; hh[6] = (__bf16)v1.z; hh[7] = (__bf16)v1.w;
        *(bf16x8*)&sA[r * E_SZ + ((s8 ^ (r & 15)) << 3)] = hh;
    }
#pragma unroll
    for (int k = 0; k < 4; ++k) {
        int i = tid + k * 512;
        int r = i >> 4, s8 = i & 15;
        const float* src = kern + ((size_t)r * P_SZ + p) * E_SZ + s8 * 8;
        float4 v0 = *(const float4*)src;
        float4 v1 = *(const float4*)(src + 4);
        bf16x8 hh;
        hh[0] = (__bf16)v0.x; hh[1] = (__bf16)v0.y; hh[2] = (__bf16)v0.z; hh[3] = (__bf16)v0.w;
        hh[4] = (__bf16)v1.x; hh[5] = (__bf16)v1.y; hh[6] = (__bf16)v1.z; hh[7] = (__bf16)v1.w;
        *(bf16x8*)&sB[r * E_SZ + ((s8 ^ (r & 15)) << 3)] = hh;
    }
    __syncthreads();

    const int w = tid >> 6, lane = tid & 63;
    const int l31 = lane & 31, hi = lane >> 5;
    const int mh = w >> 2, ng = w & 3;

    f32x16 acc[2];
#pragma unroll
    for (int mt = 0; mt < 2; ++mt)
#pragma unroll
        for (int j = 0; j < 16; ++j) acc[mt][j] = 0.f;

    const int brow = ng * 32 + l31;
#pragma unroll
    for (int kk = 0; kk < 8; ++kk) {
        const int e8 = kk * 2 + hi;
        bf16x8 bfr = *(const bf16x8*)&sA[brow * E_SZ + ((e8 ^ (brow & 15)) << 3)];
#pragma unroll
        for (int mt = 0; mt < 2; ++mt) {
            int arow = (mh * 2 + mt) * 32 + l31;
            bf16x8 afr = *(const bf16x8*)&sB[arow * E_SZ + ((e8 ^ (arow & 15)) << 3)];
            acc[mt] = __builtin_amdgcn_mfma_f32_32x32x16_bf16(afr, bfr, acc[mt], 0, 0, 0);
        }
    }

    const float* xqp = x + ((size_t)(b0 + brow) * F_SZ + fq) * E_SZ;
    float sv = 0.f;
#pragma unroll
    for (int mt = 0; mt < 2; ++mt) {
        const int dbase = (mh * 2 + mt) * 32 + hi * 4;
#pragma unroll
        for (int q = 0; q < 4; ++q) {
            float4 xq = *(const float4*)(xqp + dbase + q * 8);
            sv += acc[mt][q * 4 + 0] * xq.x + acc[mt][q * 4 + 1] * xq.y
                + acc[mt][q * 4 + 2] * xq.z + acc[mt][q * 4 + 3] * xq.w;
        }
    }
    sv += __shfl_xor(sv, 32);
    if (hi == 0) red[mh][brow] = sv;
    __syncthreads();

    if (tid < 128)
        out[(size_t)(b0 + tid) * P_SZ + p] = red[0][tid] + red[1][tid];
}

extern "C" void kernel_launch(void* const* d_in, const int* in_sizes, int n_in,
                              void* d_out, int out_size, void* d_ws, size_t ws_size,
                              hipStream_t stream) {
    const float* x    = (const float*)d_in[0];   // [2048, 24, 128] f32
    const float* kern = (const float*)d_in[1];   // [128, 276, 128] f32
    float* out = (float*)d_out;                  // [2048, 276] f32

    if (ws_size >= WS_NEED) {
        __bf16* xft = (__bf16*)d_ws;
        prepack_x<<<dim3(XPREP_BLKS), 256, 0, stream>>>(x, xft);
        opn_main<<<dim3(NWG), 512, 0, stream>>>(xft, kern, out);
    } else {
        opn_fallback<<<dim3(P_SZ * 16), 512, 0, stream>>>(x, kern, out);
    }
}

// Round 15
// 51.666 us; speedup vs baseline: 2.2241x; 2.2241x over previous
//
#include <hip/hip_runtime.h>
#include <stdint.h>

#define B_SZ 2048
#define F_SZ 24
#define E_SZ 128
#define P_SZ 276            // F*(F-1)/2
#define BT   256            // batch rows per block
#define NWG  (P_SZ * 8)     // 2208: orig&7 = batch tile (one per XCD)

#define XT_ELEMS (B_SZ * F_SZ * E_SZ)   // 6,291,456 (12.6 MB bf16)
#define KB_ELEMS (P_SZ * E_SZ * E_SZ)   // 4,521,984 ( 9.0 MB bf16)
#define WS_NEED  ((size_t)(XT_ELEMS + KB_ELEMS) * 2)

#define XPREP_BLKS (F_SZ * 64)          // 1536
#define KPREP_BLKS (KB_ELEMS / 2048)    // 2208

typedef __bf16 bf16x8 __attribute__((ext_vector_type(8)));
typedef __bf16 bf16x4 __attribute__((ext_vector_type(4)));
typedef float  f32x16 __attribute__((ext_vector_type(16)));

// ---- prepack (verified coalesced, from R11) ---------------------------------
// xft[f][grp<64][slot<512][8]: slot s holds
//   x[grp*32 + (s&31)][f][(s>>6)*16 + ((s>>5)&1)*8 + i]   (bf16)
// kb[p][d][slot]: pre-XOR-swizzled K so a linear LDS DMA lands swizzled.
__global__ __launch_bounds__(256) void prepack_all(
    const float* __restrict__ x, const float* __restrict__ kern,
    __bf16* __restrict__ xft, __bf16* __restrict__ kb)
{
    const int bid = blockIdx.x;
    const int tid = threadIdx.x;
    if (bid < XPREP_BLKS) {
        const int f = bid >> 6, grp = bid & 63;
        __shared__ float sT[32][129];       // +1 pad: conflict-free col reads
        {
            const int row = tid >> 3, c0 = (tid & 7) * 16;
            const float* src = x + ((size_t)(grp * 32 + row) * F_SZ + f) * E_SZ + c0;
            float4 v0 = ((const float4*)src)[0];
            float4 v1 = ((const float4*)src)[1];
            float4 v2 = ((const float4*)src)[2];
            float4 v3 = ((const float4*)src)[3];
            *(float4*)&sT[row][c0]      = v0;
            *(float4*)&sT[row][c0 + 4]  = v1;
            *(float4*)&sT[row][c0 + 8]  = v2;
            *(float4*)&sT[row][c0 + 12] = v3;
        }
        __syncthreads();
        __bf16* dst = xft + (size_t)(f * 64 + grp) * 4096;
#pragma unroll
        for (int u = 0; u < 2; ++u) {
            const int s = tid * 2 + u;      // slot 0..511
            const int row = s & 31;
            const int e0  = (s >> 6) * 16 + ((s >> 5) & 1) * 8;
            bf16x8 h;
#pragma unroll
            for (int i = 0; i < 8; ++i)
                h[i] = (__bf16)sT[row][e0 + i];
            *(bf16x8*)(dst + s * 8) = h;
        }
    } else {
        int g = (bid - XPREP_BLKS) * 256 + tid;   // 16B-slot id
        int p = g >> 11, r = g & 2047;
        int d = r >> 4, s = r & 15;
        const float* src = kern + ((size_t)d * P_SZ + p) * E_SZ + ((s ^ (d & 15)) << 3);
        float4 v0 = *(const float4*)src;
        float4 v1 = *(const float4*)(src + 4);
        bf16x8 h;
        h[0] = (__bf16)v0.x; h[1] = (__bf16)v0.y; h[2] = (__bf16)v0.z; h[3] = (__bf16)v0.w;
        h[4] = (__bf16)v1.x; h[5] = (__bf16)v1.y; h[6] = (__bf16)v1.z; h[7] = (__bf16)v1.w;
        *(bf16x8*)(kb + (size_t)g * 8) = h;
    }
}

// ---- main: one block = (pair p, 256-row batch tile), 4 waves.
//      K_p: one 32KB DMA -> LDS -> each wave pulls ITS d-half as kf[2][8]
//      (32 VGPR) ONCE. Then a barrier-free loop over 4 batch groups:
//      8 xpf + 8 xq coalesced loads, 16 MFMA, lane-local dot, partial to red.
//      Wave w: dhalf = w>>1 (d in [dhalf*64, +64)), bgroups (w&1)*4 + 0..3.
//      Peak VGPR ~105 (kf32 + xpf32 + acc16 + xq8 + addr) -> no spill at
//      (256,4); LDS 34KB -> 4 blocks/CU, 16 waves/CU TLP.
__global__ __launch_bounds__(256, 4) void opn_main(
    const __bf16* __restrict__ xft, const __bf16* __restrict__ kb,
    float* __restrict__ out)
{
    __shared__ short sK[E_SZ * E_SZ];   // 32 KB swizzled K_p
    __shared__ float red[2][BT];        // per-dhalf partials, 2 KB

    const int tid = threadIdx.x, w = tid >> 6, lane = tid & 63;
    const int l31 = lane & 31, hi = lane >> 5;
    const int orig = blockIdx.x;
    const int bb = orig & 7;            // batch tile = XCD; x slice 1.6MB L2-fits
    const int p  = orig >> 3;           // 8 same-pair blocks adjacent (K L3-hot)

    int fp = 0, rem = p;
    while (rem >= F_SZ - 1 - fp) { rem -= F_SZ - 1 - fp; ++fp; }
    const int fq = fp + 1 + rem;

    // ---- K_p DMA: linear copy of pre-swizzled image (8 x 1KB per wave) ----
    const __bf16* kp = kb + (size_t)p * (E_SZ * E_SZ);
#pragma unroll
    for (int t = 0; t < 8; ++t) {
        const int base = (w * 8 + t) * 64;
        __builtin_amdgcn_global_load_lds(
            (const __attribute__((address_space(1))) void*)(kp + (size_t)(base + lane) * 8),
            (__attribute__((address_space(3))) void*)(&sK[base * 8]),
            16, 0, 0);
    }
    __syncthreads();                    // drains DMA

    // ---- pull THIS WAVE'S d-half into registers, once: kf[2][8] = 32 VGPR ----
    const int dhalf = w >> 1;
    bf16x8 kf[2][8];
#pragma unroll
    for (int mtl = 0; mtl < 2; ++mtl) {
        const int arow = (dhalf * 2 + mtl) * 32 + l31;
        const short* kRow = &sK[arow * E_SZ];
        const int asw = (arow & 15) << 3;
#pragma unroll
        for (int kk = 0; kk < 8; ++kk)
            kf[mtl][kk] = *(const bf16x8*)&kRow[((kk * 2 + hi) << 3) ^ asw];
    }

    // ---- 4 batch groups, barrier-free; NOT unrolled (spill-proof) ----
#pragma unroll 1
    for (int j = 0; j < 4; ++j) {
        const int g   = (w & 1) * 4 + j;        // bgroup 0..7 within tile
        const int grp = bb * 8 + g;             // global 32-row group

        // Xp B-fragments: 8 coalesced dwordx4
        bf16x8 xpf[8];
        const __bf16* xpb = xft + (size_t)(fp * 64 + grp) * 4096 + lane * 8;
#pragma unroll
        for (int kk = 0; kk < 8; ++kk)
            xpf[kk] = *(const bf16x8*)(xpb + kk * 512);

        const __bf16* xqb = xft + (size_t)(fq * 64 + grp) * 4096 + l31 * 8 + hi * 4;

        // D layout: col = lane&31 (= b), row(d) = (reg&3)+8*(reg>>2)+4*hi+32mt
        float s0 = 0.f, s1 = 0.f;
#pragma unroll
        for (int mtl = 0; mtl < 2; ++mtl) {
            const int mt = dhalf * 2 + mtl;
            bf16x4 xq0 = *(const bf16x4*)(xqb + (mt * 2 + 0) * 512 + 0);
            bf16x4 xq1 = *(const bf16x4*)(xqb + (mt * 2 + 0) * 512 + 256);
            bf16x4 xq2 = *(const bf16x4*)(xqb + (mt * 2 + 1) * 512 + 0);
            bf16x4 xq3 = *(const bf16x4*)(xqb + (mt * 2 + 1) * 512 + 256);
            f32x16 acc;
#pragma unroll
            for (int q = 0; q < 16; ++q) acc[q] = 0.f;
#pragma unroll
            for (int kk = 0; kk < 8; ++kk)
                acc = __builtin_amdgcn_mfma_f32_32x32x16_bf16(kf[mtl][kk], xpf[kk], acc, 0, 0, 0);
            s0 += acc[ 0] * (float)xq0[0] + acc[ 1] * (float)xq0[1]
                + acc[ 2] * (float)xq0[2] + acc[ 3] * (float)xq0[3];
            s1 += acc[ 4] * (float)xq1[0] + acc[ 5] * (float)xq1[1]
                + acc[ 6] * (float)xq1[2] + acc[ 7] * (float)xq1[3];
            s0 += acc[ 8] * (float)xq2[0] + acc[ 9] * (float)xq2[1]
                + acc[10] * (float)xq2[2] + acc[11] * (float)xq2[3];
            s1 += acc[12] * (float)xq3[0] + acc[13] * (float)xq3[1]
                + acc[14] * (float)xq3[2] + acc[15] * (float)xq3[3];
        }
        float s = s0 + s1;
        s += __shfl_xor(s, 32);                 // combine the two hi row-groups
        if (hi == 0) red[dhalf][g * 32 + l31] = s;
    }
    __syncthreads();

    // combine d-halves and store out[b, p] (256 rows)
    out[(size_t)(bb * BT + tid) * P_SZ + p] = red[0][tid] + red[1][tid];
}

// ---------------- fallback (round-2 kernel, used if ws too small) -----------
__global__ __launch_bounds__(512, 4) void opn_fallback(
    const float* __restrict__ x, const float* __restrict__ kern,
    float* __restrict__ out)
{
    __shared__ short sA[128 * E_SZ];
    __shared__ short sB[E_SZ * E_SZ];
    __shared__ float red[2][128];

    const int tid = threadIdx.x;
    const int orig = blockIdx.x;
    const int nwg2 = P_SZ * 16;
    const int wgid = (orig & 7) * (nwg2 / 8) + (orig >> 3);
    const int p  = wgid >> 4;
    const int bb = wgid & 15;
    const int b0 = bb * 128;

    int fp = 0, rem = p;
    while (rem >= F_SZ - 1 - fp) { rem -= F_SZ - 1 - fp; ++fp; }
    const int fq = fp + 1 + rem;

#pragma unroll
    for (int k = 0; k < 4; ++k) {
        int i = tid + k * 512;
        int r = i >> 4, s8 = i & 15;
        const float* src = x + ((size_t)(b0 + r) * F_SZ + fp) * E_SZ + s8 * 8;
        float4 v0 = *(const float4*)src;
        float4 v1 = *(const float4*)(src + 4);
        bf16x8 hh;
        hh[0] = (__bf16)v0.x; hh[1] = (__bf16)v0.y; hh[2] = (__bf16)v0.z; hh[3] = (__bf16)v0.w;
        hh[4] = (__bf16)v1.x; hh[5] = (__bf16)v1.y; hh[6] = (__bf16)v1.z; hh[7] = (__bf16)v1.w;
        *(bf16x8*)&sA[r * E_SZ + ((s8 ^ (r & 15)) << 3)] = hh;
    }
#pragma unroll
    for (int k = 0; k < 4; ++k) {
        int i = tid + k * 512;
        int r = i >> 4, s8 = i & 15;
        const float* src = kern + ((size_t)r * P_SZ + p) * E_SZ + s8 * 8;
        float4 v0 = *(const float4*)src;
        float4 v1 = *(const float4*)(src + 4);
        bf16x8 hh;
        hh[0] = (__bf16)v0.x; hh[1] = (__bf16)v0.y; hh[2] = (__bf16)v0.z; hh[3] = (__bf16)v0.w;
        hh[4] = (__bf16)v1.x; hh[5] = (__bf16)v1.y; hh[6] = (__bf16)v1.z; hh[7] = (__bf16)v1.w;
        *(bf16x8*)&sB[r * E_SZ + ((s8 ^ (r & 15)) << 3)] = hh;
    }
    __syncthreads();

    const int w = tid >> 6, lane = tid & 63;
    const int l31 = lane & 31, hi = lane >> 5;
    const int mh = w >> 2, ng = w & 3;

    f32x16 acc[2];
#pragma unroll
    for (int mt = 0; mt < 2; ++mt)
#pragma unroll
        for (int j = 0; j < 16; ++j) acc[mt][j] = 0.f;

    const int brow = ng * 32 + l31;
#pragma unroll
    for (int kk = 0; kk < 8; ++kk) {
        const int e8 = kk * 2 + hi;
        bf16x8 bfr = *(const bf16x8*)&sA[brow * E_SZ + ((e8 ^ (brow & 15)) << 3)];
#pragma unroll
        for (int mt = 0; mt < 2; ++mt) {
            int arow = (mh * 2 + mt) * 32 + l31;
            bf16x8 afr = *(const bf16x8*)&sB[arow * E_SZ + ((e8 ^ (arow & 15)) << 3)];
            acc[mt] = __builtin_amdgcn_mfma_f32_32x32x16_bf16(afr, bfr, acc[mt], 0, 0, 0);
        }
    }

    const float* xqp = x + ((size_t)(b0 + brow) * F_SZ + fq) * E_SZ;
    float sv = 0.f;
#pragma unroll
    for (int mt = 0; mt < 2; ++mt) {
        const int dbase = (mh * 2 + mt) * 32 + hi * 4;
#pragma unroll
        for (int q = 0; q < 4; ++q) {
            float4 xq = *(const float4*)(xqp + dbase + q * 8);
            sv += acc[mt][q * 4 + 0] * xq.x + acc[mt][q * 4 + 1] * xq.y
                + acc[mt][q * 4 + 2] * xq.z + acc[mt][q * 4 + 3] * xq.w;
        }
    }
    sv += __shfl_xor(sv, 32);
    if (hi == 0) red[mh][brow] = sv;
    __syncthreads();

    if (tid < 128)
        out[(size_t)(b0 + tid) * P_SZ + p] = red[0][tid] + red[1][tid];
}

extern "C" void kernel_launch(void* const* d_in, const int* in_sizes, int n_in,
                              void* d_out, int out_size, void* d_ws, size_t ws_size,
                              hipStream_t stream) {
    const float* x    = (const float*)d_in[0];   // [2048, 24, 128] f32
    const float* kern = (const float*)d_in[1];   // [128, 276, 128] f32
    float* out = (float*)d_out;                  // [2048, 276] f32

    if (ws_size >= WS_NEED) {
        __bf16* xft = (__bf16*)d_ws;
        __bf16* kb  = xft + XT_ELEMS;
        prepack_all<<<dim3(XPREP_BLKS + KPREP_BLKS), 256, 0, stream>>>(x, kern, xft, kb);
        opn_main<<<dim3(NWG), 256, 0, stream>>>(xft, kb, out);
    } else {
        opn_fallback<<<dim3(P_SZ * 16), 512, 0, stream>>>(x, kern, out);
    }
}

// Round 16
// 49.398 us; speedup vs baseline: 2.3262x; 1.0459x over previous
//
#include <hip/hip_runtime.h>
#include <stdint.h>

#define B_SZ 2048
#define F_SZ 24
#define E_SZ 128
#define P_SZ 276            // F*(F-1)/2
#define BT   256            // batch rows per block
#define NWG  (P_SZ * 8)     // 2208: orig&7 = batch tile (one per XCD)

#define XT_ELEMS (B_SZ * F_SZ * E_SZ)   // 6,291,456 (12.6 MB bf16)
#define KB_ELEMS (P_SZ * E_SZ * E_SZ)   // 4,521,984 ( 9.0 MB bf16)
#define WS_NEED  ((size_t)(XT_ELEMS + KB_ELEMS) * 2)

#define XPREP_BLKS (F_SZ * 64)          // 1536
#define KPREP_BLKS (KB_ELEMS / 2048)    // 2208

typedef __bf16 bf16x8 __attribute__((ext_vector_type(8)));
typedef __bf16 bf16x4 __attribute__((ext_vector_type(4)));
typedef float  f32x16 __attribute__((ext_vector_type(16)));

// ---- prepack (verified coalesced, from R11/R15) ------------------------------
// xft[f][grp<64][slot<512][8]: slot s holds
//   x[grp*32 + (s&31)][f][(s>>6)*16 + ((s>>5)&1)*8 + i]   (bf16)
// kb[p][d][slot]: pre-XOR-swizzled K so a linear LDS DMA lands swizzled.
__global__ __launch_bounds__(256) void prepack_all(
    const float* __restrict__ x, const float* __restrict__ kern,
    __bf16* __restrict__ xft, __bf16* __restrict__ kb)
{
    const int bid = blockIdx.x;
    const int tid = threadIdx.x;
    if (bid < XPREP_BLKS) {
        const int f = bid >> 6, grp = bid & 63;
        __shared__ float sT[32][129];       // +1 pad: conflict-free col reads
        {
            const int row = tid >> 3, c0 = (tid & 7) * 16;
            const float* src = x + ((size_t)(grp * 32 + row) * F_SZ + f) * E_SZ + c0;
            float4 v0 = ((const float4*)src)[0];
            float4 v1 = ((const float4*)src)[1];
            float4 v2 = ((const float4*)src)[2];
            float4 v3 = ((const float4*)src)[3];
            *(float4*)&sT[row][c0]      = v0;
            *(float4*)&sT[row][c0 + 4]  = v1;
            *(float4*)&sT[row][c0 + 8]  = v2;
            *(float4*)&sT[row][c0 + 12] = v3;
        }
        __syncthreads();
        __bf16* dst = xft + (size_t)(f * 64 + grp) * 4096;
#pragma unroll
        for (int u = 0; u < 2; ++u) {
            const int s = tid * 2 + u;      // slot 0..511
            const int row = s & 31;
            const int e0  = (s >> 6) * 16 + ((s >> 5) & 1) * 8;
            bf16x8 h;
#pragma unroll
            for (int i = 0; i < 8; ++i)
                h[i] = (__bf16)sT[row][e0 + i];
            *(bf16x8*)(dst + s * 8) = h;
        }
    } else {
        int g = (bid - XPREP_BLKS) * 256 + tid;   // 16B-slot id
        int p = g >> 11, r = g & 2047;
        int d = r >> 4, s = r & 15;
        const float* src = kern + ((size_t)d * P_SZ + p) * E_SZ + ((s ^ (d & 15)) << 3);
        float4 v0 = *(const float4*)src;
        float4 v1 = *(const float4*)(src + 4);
        bf16x8 h;
        h[0] = (__bf16)v0.x; h[1] = (__bf16)v0.y; h[2] = (__bf16)v0.z; h[3] = (__bf16)v0.w;
        h[4] = (__bf16)v1.x; h[5] = (__bf16)v1.y; h[6] = (__bf16)v1.z; h[7] = (__bf16)v1.w;
        *(bf16x8*)(kb + (size_t)g * 8) = h;
    }
}

// ---- main: one block = (pair p, 256-row batch tile), 4 waves.
//      Identical dataflow to R15 BUT: __launch_bounds__(256,3) caps VGPR at
//      ~170 (not 64!) so kf[2][8] + xpf[2][8] + acc all stay RESIDENT, and the
//      xpf stream is depth-1 software-pipelined (issue j+1's 8 loads before
//      computing j; tile-0's loads issued before the DMA-drain barrier).
//      The R12-R15 plateau (43us, VGPR=64) was the compiler's occupancy-first
//      regalloc serializing loads -- this kernel tests exactly that theory.
__global__ __launch_bounds__(256, 3) void opn_main(
    const __bf16* __restrict__ xft, const __bf16* __restrict__ kb,
    float* __restrict__ out)
{
    __shared__ short sK[E_SZ * E_SZ];   // 32 KB swizzled K_p
    __shared__ float red[2][BT];        // per-dhalf partials, 2 KB

    const int tid = threadIdx.x, w = tid >> 6, lane = tid & 63;
    const int l31 = lane & 31, hi = lane >> 5;
    const int orig = blockIdx.x;
    const int bb = orig & 7;            // batch tile = XCD; x slice 1.6MB L2-fits
    const int p  = orig >> 3;           // 8 same-pair blocks adjacent (K L3-hot)

    int fp = 0, rem = p;
    while (rem >= F_SZ - 1 - fp) { rem -= F_SZ - 1 - fp; ++fp; }
    const int fq = fp + 1 + rem;

    // ---- K_p DMA: linear copy of pre-swizzled image (8 x 1KB per wave) ----
    const __bf16* kp = kb + (size_t)p * (E_SZ * E_SZ);
#pragma unroll
    for (int t = 0; t < 8; ++t) {
        const int base = (w * 8 + t) * 64;
        __builtin_amdgcn_global_load_lds(
            (const __attribute__((address_space(1))) void*)(kp + (size_t)(base + lane) * 8),
            (__attribute__((address_space(3))) void*)(&sK[base * 8]),
            16, 0, 0);
    }

    // ---- tile-0 xpf loads issued BEFORE the barrier (hide under DMA drain) --
    const __bf16* xpbase = xft + (size_t)fp * 64 * 4096 + lane * 8;
    bf16x8 xpf[2][8];
    {
        const int grp0 = bb * 8 + (w & 1) * 4;   // j = 0
        const __bf16* xpb = xpbase + (size_t)grp0 * 4096;
#pragma unroll
        for (int kk = 0; kk < 8; ++kk)
            xpf[0][kk] = *(const bf16x8*)(xpb + kk * 512);
    }

    __syncthreads();                    // drains DMA (x loads complete under it)

    // ---- pull THIS WAVE'S d-half into registers, once: kf[2][8] = 32 VGPR ----
    const int dhalf = w >> 1;
    bf16x8 kf[2][8];
#pragma unroll
    for (int mtl = 0; mtl < 2; ++mtl) {
        const int arow = (dhalf * 2 + mtl) * 32 + l31;
        const short* kRow = &sK[arow * E_SZ];
        const int asw = (arow & 15) << 3;
#pragma unroll
        for (int kk = 0; kk < 8; ++kk)
            kf[mtl][kk] = *(const bf16x8*)&kRow[((kk * 2 + hi) << 3) ^ asw];
    }

    // ---- 4 batch groups, fully unrolled, xpf depth-1 pipelined ----
#pragma unroll
    for (int j = 0; j < 4; ++j) {
        const int g   = (w & 1) * 4 + j;        // bgroup 0..7 within tile
        const int grp = bb * 8 + g;             // global 32-row group

        if (j + 1 < 4) {                        // issue next tile's xpf NOW
            const __bf16* xpb = xpbase + (size_t)(grp + 1) * 4096;
#pragma unroll
            for (int kk = 0; kk < 8; ++kk)
                xpf[(j + 1) & 1][kk] = *(const bf16x8*)(xpb + kk * 512);
        }

        const __bf16* xqb = xft + (size_t)(fq * 64 + grp) * 4096 + l31 * 8 + hi * 4;

        // D layout: col = lane&31 (= b), row(d) = (reg&3)+8*(reg>>2)+4*hi+32mt
        float s0 = 0.f, s1 = 0.f;
#pragma unroll
        for (int mtl = 0; mtl < 2; ++mtl) {
            const int mt = dhalf * 2 + mtl;
            bf16x4 xq0 = *(const bf16x4*)(xqb + (mt * 2 + 0) * 512 + 0);
            bf16x4 xq1 = *(const bf16x4*)(xqb + (mt * 2 + 0) * 512 + 256);
            bf16x4 xq2 = *(const bf16x4*)(xqb + (mt * 2 + 1) * 512 + 0);
            bf16x4 xq3 = *(const bf16x4*)(xqb + (mt * 2 + 1) * 512 + 256);
            f32x16 acc;
#pragma unroll
            for (int q = 0; q < 16; ++q) acc[q] = 0.f;
#pragma unroll
            for (int kk = 0; kk < 8; ++kk)
                acc = __builtin_amdgcn_mfma_f32_32x32x16_bf16(kf[mtl][kk], xpf[j & 1][kk], acc, 0, 0, 0);
            s0 += acc[ 0] * (float)xq0[0] + acc[ 1] * (float)xq0[1]
                + acc[ 2] * (float)xq0[2] + acc[ 3] * (float)xq0[3];
            s1 += acc[ 4] * (float)xq1[0] + acc[ 5] * (float)xq1[1]
                + acc[ 6] * (float)xq1[2] + acc[ 7] * (float)xq1[3];
            s0 += acc[ 8] * (float)xq2[0] + acc[ 9] * (float)xq2[1]
                + acc[10] * (float)xq2[2] + acc[11] * (float)xq2[3];
            s1 += acc[12] * (float)xq3[0] + acc[13] * (float)xq3[1]
                + acc[14] * (float)xq3[2] + acc[15] * (float)xq3[3];
        }
        float s = s0 + s1;
        s += __shfl_xor(s, 32);                 // combine the two hi row-groups
        if (hi == 0) red[dhalf][g * 32 + l31] = s;
    }
    __syncthreads();

    // combine d-halves and store out[b, p] (256 rows)
    out[(size_t)(bb * BT + tid) * P_SZ + p] = red[0][tid] + red[1][tid];
}

// ---------------- fallback (round-2 kernel, used if ws too small) -----------
__global__ __launch_bounds__(512, 4) void opn_fallback(
    const float* __restrict__ x, const float* __restrict__ kern,
    float* __restrict__ out)
{
    __shared__ short sA[128 * E_SZ];
    __shared__ short sB[E_SZ * E_SZ];
    __shared__ float red[2][128];

    const int tid = threadIdx.x;
    const int orig = blockIdx.x;
    const int nwg2 = P_SZ * 16;
    const int wgid = (orig & 7) * (nwg2 / 8) + (orig >> 3);
    const int p  = wgid >> 4;
    const int bb = wgid & 15;
    const int b0 = bb * 128;

    int fp = 0, rem = p;
    while (rem >= F_SZ - 1 - fp) { rem -= F_SZ - 1 - fp; ++fp; }
    const int fq = fp + 1 + rem;

#pragma unroll
    for (int k = 0; k < 4; ++k) {
        int i = tid + k * 512;
        int r = i >> 4, s8 = i & 15;
        const float* src = x + ((size_t)(b0 + r) * F_SZ + fp) * E_SZ + s8 * 8;
        float4 v0 = *(const float4*)src;
        float4 v1 = *(const float4*)(src + 4);
        bf16x8 hh;
        hh[0] = (__bf16)v0.x; hh[1] = (__bf16)v0.y; hh[2] = (__bf16)v0.z; hh[3] = (__bf16)v0.w;
        hh[4] = (__bf16)v1.x; hh[5] = (__bf16)v1.y; hh[6] = (__bf16)v1.z; hh[7] = (__bf16)v1.w;
        *(bf16x8*)&sA[r * E_SZ + ((s8 ^ (r & 15)) << 3)] = hh;
    }
#pragma unroll
    for (int k = 0; k < 4; ++k) {
        int i = tid + k * 512;
        int r = i >> 4, s8 = i & 15;
        const float* src = kern + ((size_t)r * P_SZ + p) * E_SZ + s8 * 8;
        float4 v0 = *(const float4*)src;
        float4 v1 = *(const float4*)(src + 4);
        bf16x8 hh;
        hh[0] = (__bf16)v0.x; hh[1] = (__bf16)v0.y; hh[2] = (__bf16)v0.z; hh[3] = (__bf16)v0.w;
        hh[4] = (__bf16)v1.x; hh[5] = (__bf16)v1.y; hh[6] = (__bf16)v1.z; hh[7] = (__bf16)v1.w;
        *(bf16x8*)&sB[r * E_SZ + ((s8 ^ (r & 15)) << 3)] = hh;
    }
    __syncthreads();

    const int w = tid >> 6, lane = tid & 63;
    const int l31 = lane & 31, hi = lane >> 5;
    const int mh = w >> 2, ng = w & 3;

    f32x16 acc[2];
#pragma unroll
    for (int mt = 0; mt < 2; ++mt)
#pragma unroll
        for (int j = 0; j < 16; ++j) acc[mt][j] = 0.f;

    const int brow = ng * 32 + l31;
#pragma unroll
    for (int kk = 0; kk < 8; ++kk) {
        const int e8 = kk * 2 + hi;
        bf16x8 bfr = *(const bf16x8*)&sA[brow * E_SZ + ((e8 ^ (brow & 15)) << 3)];
#pragma unroll
        for (int mt = 0; mt < 2; ++mt) {
            int arow = (mh * 2 + mt) * 32 + l31;
            bf16x8 afr = *(const bf16x8*)&sB[arow * E_SZ + ((e8 ^ (arow & 15)) << 3)];
            acc[mt] = __builtin_amdgcn_mfma_f32_32x32x16_bf16(afr, bfr, acc[mt], 0, 0, 0);
        }
    }

    const float* xqp = x + ((size_t)(b0 + brow) * F_SZ + fq) * E_SZ;
    float sv = 0.f;
#pragma unroll
    for (int mt = 0; mt < 2; ++mt) {
        const int dbase = (mh * 2 + mt) * 32 + hi * 4;
#pragma unroll
        for (int q = 0; q < 4; ++q) {
            float4 xq = *(const float4*)(xqp + dbase + q * 8);
            sv += acc[mt][q * 4 + 0] * xq.x + acc[mt][q * 4 + 1] * xq.y
                + acc[mt][q * 4 + 2] * xq.z + acc[mt][q * 4 + 3] * xq.w;
        }
    }
    sv += __shfl_xor(sv, 32);
    if (hi == 0) red[mh][brow] = sv;
    __syncthreads();

    if (tid < 128)
        out[(size_t)(b0 + tid) * P_SZ + p] = red[0][tid] + red[1][tid];
}

extern "C" void kernel_launch(void* const* d_in, const int* in_sizes, int n_in,
                              void* d_out, int out_size, void* d_ws, size_t ws_size,
                              hipStream_t stream) {
    const float* x    = (const float*)d_in[0];   // [2048, 24, 128] f32
    const float* kern = (const float*)d_in[1];   // [128, 276, 128] f32
    float* out = (float*)d_out;                  // [2048, 276] f32

    if (ws_size >= WS_NEED) {
        __bf16* xft = (__bf16*)d_ws;
        __bf16* kb  = xft + XT_ELEMS;
        prepack_all<<<dim3(XPREP_BLKS + KPREP_BLKS), 256, 0, stream>>>(x, kern, xft, kb);
        opn_main<<<dim3(NWG), 256, 0, stream>>>(xft, kb, out);
    } else {
        opn_fallback<<<dim3(P_SZ * 16), 512, 0, stream>>>(x, kern, out);
    }
}